// Round 1
// baseline (3041.640 us; speedup 1.0000x reference)
//
#include <hip/hip_runtime.h>

#define NSAMP 1000000
#define NFEAT 64
#define NCLUS 128
#define NITER 5
#define NPART 64
#define ABLOCKS 512
#define ATHREADS 256

// ---------------- prep: Ct/c2 from init centroids, zero accumulators ----------------
__global__ void prep_kernel(const float* __restrict__ C0, float* __restrict__ Ct,
                            float* __restrict__ c2, float* __restrict__ psum,
                            float* __restrict__ pcount, float* __restrict__ inert) {
    int k = blockIdx.x;    // 0..127
    int f = threadIdx.x;   // 0..63
    float v = C0[k * NFEAT + f];
    Ct[f * NCLUS + k] = v;
    float s = v * v;
    #pragma unroll
    for (int off = 32; off; off >>= 1) s += __shfl_down(s, off);
    if (f == 0) c2[k] = s;

    int tid = k * 64 + f;  // 0..8191
    for (int idx = tid; idx < NPART * NCLUS * NFEAT; idx += 8192) psum[idx] = 0.f;
    for (int idx = tid; idx < NPART * NCLUS; idx += 8192) pcount[idx] = 0.f;
    if (tid < NITER) inert[tid] = 0.f;
}

// ---------------- assign: distances + argmin + fused LDS accumulation ----------------
__global__ __launch_bounds__(ATHREADS) void assign_kernel(
    const float* __restrict__ X, const float* __restrict__ Ct,
    const float* __restrict__ c2g, float* __restrict__ labelsF,
    float* __restrict__ psum, float* __restrict__ pcount,
    float* __restrict__ inertOut) {
    __shared__ float lsum[NCLUS * 65];   // pad 65: bank = (65k+f)%32 spreads labels
    __shared__ float lcount[NCLUS];
    __shared__ float linert;

    int tid = threadIdx.x;
    for (int i = tid; i < NCLUS * 65; i += ATHREADS) lsum[i] = 0.f;
    if (tid < NCLUS) lcount[tid] = 0.f;
    if (tid == 0) linert = 0.f;
    __syncthreads();

    float my_in = 0.f;
    for (int i = blockIdx.x * ATHREADS + tid; i < NSAMP; i += ABLOCKS * ATHREADS) {
        // sample features -> registers (fully unrolled: static indexing only)
        float x[NFEAT];
        const float4* xp = (const float4*)(X + (size_t)i * NFEAT);
        #pragma unroll
        for (int j = 0; j < 16; ++j) {
            float4 v = xp[j];
            x[4 * j + 0] = v.x; x[4 * j + 1] = v.y;
            x[4 * j + 2] = v.z; x[4 * j + 3] = v.w;
        }
        float x2 = 0.f;
        #pragma unroll
        for (int f = 0; f < NFEAT; ++f) x2 = __builtin_fmaf(x[f], x[f], x2);

        float best = 3.4e38f;
        int bidx = 0;
        for (int kc = 0; kc < NCLUS; kc += 8) {
            float acc[8] = {0.f, 0.f, 0.f, 0.f, 0.f, 0.f, 0.f, 0.f};
            #pragma unroll
            for (int f = 0; f < NFEAT; ++f) {
                const float* cp = Ct + f * NCLUS + kc;   // wave-uniform address
                #pragma unroll
                for (int j = 0; j < 8; ++j)
                    acc[j] = __builtin_fmaf(x[f], cp[j], acc[j]);
            }
            #pragma unroll
            for (int j = 0; j < 8; ++j) {
                float m = __builtin_fmaf(-2.f, acc[j], c2g[kc + j]);
                if (m < best) { best = m; bidx = kc + j; }   // strict <: first-min wins
            }
        }
        labelsF[i] = (float)bidx;          // harness reads outputs as f32
        float d2 = x2 + best;
        if (d2 < 0.f) d2 = 0.f;
        my_in += d2;

        #pragma unroll
        for (int f = 0; f < NFEAT; ++f) atomicAdd(&lsum[bidx * 65 + f], x[f]);
        atomicAdd(&lcount[bidx], 1.f);
    }

    // block inertia reduce
    #pragma unroll
    for (int off = 32; off; off >>= 1) my_in += __shfl_down(my_in, off);
    if ((tid & 63) == 0) atomicAdd(&linert, my_in);
    __syncthreads();

    // flush block partials to one of NPART global copies
    int part = blockIdx.x & (NPART - 1);
    for (int idx = tid; idx < NCLUS * NFEAT; idx += ATHREADS) {
        float v = lsum[(idx >> 6) * 65 + (idx & 63)];
        if (v != 0.f) atomicAdd(&psum[part * (NCLUS * NFEAT) + idx], v);
    }
    for (int idx = tid; idx < NCLUS; idx += ATHREADS) {
        float v = lcount[idx];
        if (v != 0.f) atomicAdd(&pcount[part * NCLUS + idx], v);
    }
    if (tid == 0) atomicAdd(inertOut, linert);
}

// ---------------- update: reduce partials, means/reseed, next Ct/c2 ----------------
__global__ void update_kernel(const float* __restrict__ X,
                              const int* __restrict__ reseed,   // offset for this iter
                              float* __restrict__ psum, float* __restrict__ pcount,
                              float* __restrict__ Ct, float* __restrict__ c2,
                              float* __restrict__ outC,
                              const float* __restrict__ inertIn,
                              float* __restrict__ outInert, int last) {
    int k = blockIdx.x;    // cluster
    int f = threadIdx.x;   // feature (64 threads = 1 wave)

    float s = 0.f;
    #pragma unroll 8
    for (int p = 0; p < NPART; ++p) {
        int idx = p * (NCLUS * NFEAT) + k * NFEAT + f;
        s += psum[idx];
        psum[idx] = 0.f;                  // ready for next iteration
    }
    float cnt = pcount[f * NCLUS + k];    // thread f owns partial copy p=f
    pcount[f * NCLUS + k] = 0.f;
    #pragma unroll
    for (int off = 32; off; off >>= 1) cnt += __shfl_xor(cnt, off);  // all lanes get total

    float val;
    if (cnt > 0.f) val = s / cnt;
    else           val = X[(size_t)reseed[k] * NFEAT + f];   // exact f32 reseed

    outC[k * NFEAT + f] = val;            // final iter's write survives
    Ct[f * NCLUS + k] = val;
    float q = val * val;
    #pragma unroll
    for (int off = 32; off; off >>= 1) q += __shfl_xor(q, off);
    if (f == 0) c2[k] = q;

    if (last && k == 0 && f == 0) *outInert = *inertIn;
}

extern "C" void kernel_launch(void* const* d_in, const int* in_sizes, int n_in,
                              void* d_out, int out_size, void* d_ws, size_t ws_size,
                              hipStream_t stream) {
    const float* X      = (const float*)d_in[0];
    const float* C0     = (const float*)d_in[1];
    const int*   reseed = (const int*)d_in[2];

    float* out      = (float*)d_out;
    float* outC     = out;                     // [128*64]
    float* labelsF  = out + NCLUS * NFEAT;     // [1M] labels as float
    float* outInert = out + NCLUS * NFEAT + NSAMP;  // [1]

    float* ws     = (float*)d_ws;
    float* Ct     = ws;                                  // 8192
    float* c2     = Ct + NCLUS * NFEAT;                  // 128
    float* psum   = c2 + NCLUS;                          // 64*8192
    float* pcount = psum + NPART * NCLUS * NFEAT;        // 64*128
    float* inert  = pcount + NPART * NCLUS;              // 5

    prep_kernel<<<NCLUS, 64, 0, stream>>>(C0, Ct, c2, psum, pcount, inert);
    for (int i = 0; i < NITER; ++i) {
        assign_kernel<<<ABLOCKS, ATHREADS, 0, stream>>>(X, Ct, c2, labelsF,
                                                        psum, pcount, inert + i);
        update_kernel<<<NCLUS, 64, 0, stream>>>(X, reseed + i * NCLUS, psum, pcount,
                                                Ct, c2, outC, inert + (NITER - 1),
                                                outInert, i == NITER - 1);
    }
}

// Round 2
// 2328.334 us; speedup vs baseline: 1.3064x; 1.3064x over previous
//
#include <hip/hip_runtime.h>

typedef __bf16 bf16_t;
typedef bf16_t bf16x8 __attribute__((ext_vector_type(8)));
typedef float f32x4 __attribute__((ext_vector_type(4)));

#define NSAMP 1000000
#define NFEAT 64
#define NCLUS 128
#define NITER 5
#define NPART 64
#define ABLOCKS 1024
#define ATHREADS 256
#define NTILE (NSAMP / 64)   // 15625 tiles of 64 samples (exact)

static __device__ __forceinline__ unsigned short f2b(float f) {
    return __builtin_bit_cast(unsigned short, (bf16_t)f);
}

// ---------------- prep: Cbf/c2 from init centroids, zero accumulators ----------------
__global__ void prep_centroids(const float* __restrict__ C0, bf16_t* __restrict__ Cbf,
                               float* __restrict__ c2, float* __restrict__ psum,
                               float* __restrict__ pcount, float* __restrict__ inert) {
    int k = blockIdx.x;    // 0..127
    int f = threadIdx.x;   // 0..63
    float v = C0[k * NFEAT + f];
    Cbf[k * NFEAT + f] = (bf16_t)v;
    float s = v * v;
    #pragma unroll
    for (int off = 32; off; off >>= 1) s += __shfl_down(s, off, 64);
    if (f == 0) c2[k] = s;

    int tid = k * 64 + f;  // 0..8191
    for (int idx = tid; idx < NPART * NCLUS * NFEAT; idx += 8192) psum[idx] = 0.f;
    for (int idx = tid; idx < NPART * NCLUS; idx += 8192) pcount[idx] = 0.f;
    if (tid < 8) inert[tid] = 0.f;
}

// ---------------- convert X -> bf16 (one pass, only when ws fits) ----------------
__global__ void convert_x_kernel(const float* __restrict__ X, bf16_t* __restrict__ Xbf) {
    const size_t total = (size_t)NSAMP * NFEAT / 8;   // 8M items of 8 floats
    const size_t stride = (size_t)gridDim.x * blockDim.x;
    for (size_t t = (size_t)blockIdx.x * blockDim.x + threadIdx.x; t < total; t += stride) {
        float4 v0 = ((const float4*)X)[t * 2];
        float4 v1 = ((const float4*)X)[t * 2 + 1];
        union { unsigned short us[8]; uint4 v; } u;
        u.us[0] = f2b(v0.x); u.us[1] = f2b(v0.y); u.us[2] = f2b(v0.z); u.us[3] = f2b(v0.w);
        u.us[4] = f2b(v1.x); u.us[5] = f2b(v1.y); u.us[6] = f2b(v1.z); u.us[7] = f2b(v1.w);
        ((uint4*)Xbf)[t] = u.v;
    }
}

// ---------------- assign: MFMA distances + argmin + fused accumulation ----------------
template<bool XBF>
__global__ __launch_bounds__(ATHREADS) void assign_kernel(
    const float* __restrict__ X, const bf16_t* __restrict__ Xbf,
    const bf16_t* __restrict__ Cbf, const float* __restrict__ c2g,
    float* __restrict__ labelsF, float* __restrict__ psum,
    float* __restrict__ pcount, float* __restrict__ inertOut, int last) {
    __shared__ float lsum[NCLUS * NFEAT];   // stride-64 f32: 2-way bank alias = free
    __shared__ float lcount[NCLUS];
    __shared__ float linert;

    const int tid = threadIdx.x;
    for (int i2 = tid; i2 < NCLUS * NFEAT; i2 += ATHREADS) lsum[i2] = 0.f;
    if (tid < NCLUS) lcount[tid] = 0.f;
    if (tid == 0) linert = 0.f;
    __syncthreads();

    const int lane = tid & 63;
    const int wave = tid >> 6;
    const int lr = lane & 15;   // row(A)/col(B) within 16
    const int lg = lane >> 4;   // k-group 0..3

    // All of B (C^T) in registers: lane needs Cbf[cluster t*16+lr][feat kk*32 + lg*8 + e]
    bf16x8 breg[8][2];
    float c2r[8];
    #pragma unroll
    for (int t = 0; t < 8; ++t) {
        const bf16_t* bp = Cbf + (t * 16 + lr) * NFEAT + lg * 8;
        breg[t][0] = *reinterpret_cast<const bf16x8*>(bp);
        breg[t][1] = *reinterpret_cast<const bf16x8*>(bp + 32);
        c2r[t] = c2g[t * 16 + lr];
    }

    float my_in = 0.f;
    for (int tile = blockIdx.x; tile < NTILE; tile += gridDim.x) {
        const int i0 = tile * 64 + wave * 16;   // this wave's 16 samples
        bf16x8 a0, a1;
        float px2 = 0.f;
        if constexpr (XBF) {
            const bf16_t* ap = Xbf + (size_t)(i0 + lr) * NFEAT + lg * 8;
            a0 = *reinterpret_cast<const bf16x8*>(ap);
            a1 = *reinterpret_cast<const bf16x8*>(ap + 32);
            #pragma unroll
            for (int e = 0; e < 8; ++e) {
                float f0 = (float)a0[e], f1 = (float)a1[e];
                px2 = __builtin_fmaf(f0, f0, px2);
                px2 = __builtin_fmaf(f1, f1, px2);
            }
        } else {
            const float* ap = X + (size_t)(i0 + lr) * NFEAT + lg * 8;
            float4 v0 = *(const float4*)ap,        v1 = *(const float4*)(ap + 4);
            float4 v2 = *(const float4*)(ap + 32), v3 = *(const float4*)(ap + 36);
            a0[0] = (bf16_t)v0.x; a0[1] = (bf16_t)v0.y; a0[2] = (bf16_t)v0.z; a0[3] = (bf16_t)v0.w;
            a0[4] = (bf16_t)v1.x; a0[5] = (bf16_t)v1.y; a0[6] = (bf16_t)v1.z; a0[7] = (bf16_t)v1.w;
            a1[0] = (bf16_t)v2.x; a1[1] = (bf16_t)v2.y; a1[2] = (bf16_t)v2.z; a1[3] = (bf16_t)v2.w;
            a1[4] = (bf16_t)v3.x; a1[5] = (bf16_t)v3.y; a1[6] = (bf16_t)v3.z; a1[7] = (bf16_t)v3.w;
            px2 = v0.x*v0.x + v0.y*v0.y + v0.z*v0.z + v0.w*v0.w
                + v1.x*v1.x + v1.y*v1.y + v1.z*v1.z + v1.w*v1.w
                + v2.x*v2.x + v2.y*v2.y + v2.z*v2.z + v2.w*v2.w
                + v3.x*v3.x + v3.y*v3.y + v3.z*v3.z + v3.w*v3.w;
        }
        // combine the 4 k-groups: lanes {lr, lr+16, lr+32, lr+48} all get x2 of sample i0+lr
        px2 += __shfl_xor(px2, 16, 64);
        px2 += __shfl_xor(px2, 32, 64);

        f32x4 zero = {0.f, 0.f, 0.f, 0.f};
        f32x4 acc[8];
        #pragma unroll
        for (int t = 0; t < 8; ++t) acc[t] = zero;
        #pragma unroll
        for (int t = 0; t < 8; ++t) {
            acc[t] = __builtin_amdgcn_mfma_f32_16x16x32_bf16(a0, breg[t][0], acc[t], 0, 0, 0);
            acc[t] = __builtin_amdgcn_mfma_f32_16x16x32_bf16(a1, breg[t][1], acc[t], 0, 0, 0);
        }
        // acc[t][r] = dot(sample i0 + lg*4 + r, cluster t*16 + lr)

        // per-lane argmin over the 8 col-tiles (ascending cluster idx -> strict < keeps first)
        float bv[4]; int bi[4];
        #pragma unroll
        for (int r = 0; r < 4; ++r) {
            bv[r] = __builtin_fmaf(-2.f, acc[0][r], c2r[0]);
            bi[r] = lr;
        }
        #pragma unroll
        for (int t = 1; t < 8; ++t) {
            #pragma unroll
            for (int r = 0; r < 4; ++r) {
                float m = __builtin_fmaf(-2.f, acc[t][r], c2r[t]);
                bool take = m < bv[r];
                bv[r] = take ? m : bv[r];
                bi[r] = take ? t * 16 + lr : bi[r];
            }
        }
        // reduce across the 16 lanes of the group (xor of bits 0..3), first-min tie-break
        #pragma unroll
        for (int st = 1; st < 16; st <<= 1) {
            #pragma unroll
            for (int r = 0; r < 4; ++r) {
                float ov = __shfl_xor(bv[r], st, 64);
                int   oi = __shfl_xor(bi[r], st, 64);
                bool take = (ov < bv[r]) || (ov == bv[r] && oi < bi[r]);
                bv[r] = take ? ov : bv[r];
                bi[r] = take ? oi : bi[r];
            }
        }

        // per-sample: gather label/best to lane s; all lanes accumulate feature `lane`
        float myBest = 0.f; int myLab = 0;
        #pragma unroll
        for (int s = 0; s < 16; ++s) {
            const int src = (s >> 2) * 16;   // any lane of group s>>2
            int   lab = __shfl(bi[s & 3], src, 64);
            float bst = __shfl(bv[s & 3], src, 64);
            if (lane == s) { myLab = lab; myBest = bst; }
            float xv;
            if constexpr (XBF) xv = (float)Xbf[(size_t)(i0 + s) * NFEAT + lane];
            else               xv = X[(size_t)(i0 + s) * NFEAT + lane];
            atomicAdd(&lsum[lab * NFEAT + lane], xv);
        }
        if (lane < 16) {
            atomicAdd(&lcount[myLab], 1.f);
            float d2 = px2 + myBest;        // px2 on lane s IS x2 of sample i0+s
            if (d2 < 0.f) d2 = 0.f;
            my_in += d2;
            if (last) labelsF[i0 + lane] = (float)myLab;
        }
    }

    #pragma unroll
    for (int off = 32; off; off >>= 1) my_in += __shfl_down(my_in, off, 64);
    if (lane == 0) atomicAdd(&linert, my_in);
    __syncthreads();

    const int part = blockIdx.x & (NPART - 1);
    for (int idx = tid; idx < NCLUS * NFEAT; idx += ATHREADS) {
        float v = lsum[idx];
        if (v != 0.f) atomicAdd(&psum[part * (NCLUS * NFEAT) + idx], v);
    }
    for (int idx = tid; idx < NCLUS; idx += ATHREADS) {
        float v = lcount[idx];
        if (v != 0.f) atomicAdd(&pcount[part * NCLUS + idx], v);
    }
    if (tid == 0) atomicAdd(inertOut, linert);
}

// ---------------- update: reduce partials, means/reseed, next Cbf/c2 ----------------
__global__ void update_kernel(const float* __restrict__ X,
                              const int* __restrict__ reseed,
                              float* __restrict__ psum, float* __restrict__ pcount,
                              bf16_t* __restrict__ Cbf, float* __restrict__ c2,
                              float* __restrict__ outC,
                              const float* __restrict__ inertIn,
                              float* __restrict__ outInert, int last) {
    int k = blockIdx.x;    // cluster
    int f = threadIdx.x;   // feature (one wave)

    float s = 0.f;
    #pragma unroll 8
    for (int p = 0; p < NPART; ++p) {
        int idx = p * (NCLUS * NFEAT) + k * NFEAT + f;
        s += psum[idx];
        psum[idx] = 0.f;
    }
    float cnt = pcount[f * NCLUS + k];
    pcount[f * NCLUS + k] = 0.f;
    #pragma unroll
    for (int off = 32; off; off >>= 1) cnt += __shfl_xor(cnt, off, 64);

    float val;
    if (cnt > 0.f) val = s / cnt;
    else           val = X[(size_t)reseed[k] * NFEAT + f];   // exact f32 reseed

    outC[k * NFEAT + f] = val;
    Cbf[k * NFEAT + f] = (bf16_t)val;
    float q = val * val;
    #pragma unroll
    for (int off = 32; off; off >>= 1) q += __shfl_xor(q, off, 64);
    if (f == 0) c2[k] = q;

    if (last && k == 0 && f == 0) *outInert = *inertIn;
}

extern "C" void kernel_launch(void* const* d_in, const int* in_sizes, int n_in,
                              void* d_out, int out_size, void* d_ws, size_t ws_size,
                              hipStream_t stream) {
    const float* X      = (const float*)d_in[0];
    const float* C0     = (const float*)d_in[1];
    const int*   reseed = (const int*)d_in[2];

    float* out      = (float*)d_out;
    float* outC     = out;                          // [128*64]
    float* labelsF  = out + NCLUS * NFEAT;          // [1M]
    float* outInert = out + NCLUS * NFEAT + NSAMP;  // [1]

    float* ws     = (float*)d_ws;
    float* psum   = ws;                                   // 64*8192
    float* pcount = psum + NPART * NCLUS * NFEAT;         // 64*128
    float* c2     = pcount + NPART * NCLUS;               // 128
    float* inert  = c2 + NCLUS;                           // 8
    bf16_t* Cbf   = (bf16_t*)(inert + 8);                 // 8192 bf16 (16 KB)
    bf16_t* Xbf   = Cbf + NCLUS * NFEAT;                  // 64M bf16 (128 MB), optional

    const size_t base_bytes = (size_t)(NPART * NCLUS * NFEAT + NPART * NCLUS + NCLUS + 8) * 4
                            + (size_t)NCLUS * NFEAT * 2;
    const size_t need_xbf = base_bytes + (size_t)NSAMP * NFEAT * 2;
    const bool xbf = ws_size >= need_xbf;

    prep_centroids<<<NCLUS, 64, 0, stream>>>(C0, Cbf, c2, psum, pcount, inert);
    if (xbf) convert_x_kernel<<<2048, 256, 0, stream>>>(X, Xbf);

    for (int i = 0; i < NITER; ++i) {
        int last = (i == NITER - 1);
        if (xbf)
            assign_kernel<true><<<ABLOCKS, ATHREADS, 0, stream>>>(
                X, Xbf, Cbf, c2, labelsF, psum, pcount, inert + i, last);
        else
            assign_kernel<false><<<ABLOCKS, ATHREADS, 0, stream>>>(
                X, Xbf, Cbf, c2, labelsF, psum, pcount, inert + i, last);
        update_kernel<<<NCLUS, 64, 0, stream>>>(X, reseed + i * NCLUS, psum, pcount,
                                                Cbf, c2, outC, inert + (NITER - 1),
                                                outInert, last);
    }
}